// Round 1
// baseline (527.852 us; speedup 1.0000x reference)
//
#include <hip/hip_runtime.h>
#include <hip/hip_bf16.h>
#include <stdint.h>

typedef __bf16 bf16_t;
typedef __bf16 bf16x8 __attribute__((ext_vector_type(8)));
typedef __bf16 bf16x4 __attribute__((ext_vector_type(4)));
typedef float f32x4 __attribute__((ext_vector_type(4)));

#define B_ 4
#define S_ 2048
#define D_ 1024
#define H_ 16
#define DH_ 64

// ---------------- cast: fp32 -> bf16 (vectorized float4 -> bf16x4) ----------------
__global__ __launch_bounds__(256) void cast_f32_to_bf16(const float* __restrict__ in,
                                                        bf16_t* __restrict__ out, int n4) {
  int i = blockIdx.x * 256 + threadIdx.x;
  if (i < n4) {
    const float4 v = reinterpret_cast<const float4*>(in)[i];
    bf16x4 o;
    o[0] = (bf16_t)v.x; o[1] = (bf16_t)v.y; o[2] = (bf16_t)v.z; o[3] = (bf16_t)v.w;
    reinterpret_cast<bf16x4*>(out)[i] = o;
  }
}

// ---------------- transpose-cast: in [K][N] fp32 -> out [N][K] bf16 ----------------
__global__ __launch_bounds__(256) void transpose_cast(const float* __restrict__ in,
                                                      bf16_t* __restrict__ out, int K, int N) {
  __shared__ float tile[32][33];
  const int bx = blockIdx.x * 32;  // N offset
  const int by = blockIdx.y * 32;  // K offset
  const int tx = threadIdx.x & 31;
  const int ty = threadIdx.x >> 5;  // 0..7
#pragma unroll
  for (int i = 0; i < 32; i += 8)
    tile[ty + i][tx] = in[(size_t)(by + ty + i) * N + bx + tx];
  __syncthreads();
#pragma unroll
  for (int i = 0; i < 32; i += 8)
    out[(size_t)(bx + ty + i) * K + by + tx] = (bf16_t)tile[tx][ty + i];
}

// ---------------- async global->LDS 16B ----------------
__device__ __forceinline__ void gload_lds16(const bf16_t* g, bf16_t* l) {
  __builtin_amdgcn_global_load_lds((const __attribute__((address_space(1))) void*)g,
                                   (__attribute__((address_space(3))) void*)l, 16, 0, 0);
}

// ---------------- bf16 GEMM, 128x128 tile, BK=32 (m97 structure) ----------------
// A [M][K] row-major bf16, Bt [N][K] row-major bf16 (i.e. B transposed).
// MODE 0: QKV epilogue -> scatter bf16 into Q/K/V [B,H,S,Dh] with bias.
// MODE 1: proj epilogue -> fp32 Out[M][N] with bias.
template <int MODE>
__global__ __launch_bounds__(256) void gemm_bf16_128(
    const bf16_t* __restrict__ A, const bf16_t* __restrict__ Bt,
    const float* __restrict__ bias,
    bf16_t* __restrict__ Qb, bf16_t* __restrict__ Kb, bf16_t* __restrict__ Vb,
    float* __restrict__ Out, int M, int N, int K) {
  __shared__ alignas(16) bf16_t As[128 * 32];
  __shared__ alignas(16) bf16_t Bs[128 * 32];
  const int t = threadIdx.x;
  const int wave = t >> 6, lane = t & 63;
  const int r = lane & 15, g = lane >> 4;
  const int bm = blockIdx.x, bn = blockIdx.y;
  const int wm = (wave & 1) * 64, wn = (wave >> 1) * 64;

  f32x4 acc[4][4];
#pragma unroll
  for (int i = 0; i < 4; ++i)
#pragma unroll
    for (int j = 0; j < 4; ++j) acc[i][j] = f32x4{0.f, 0.f, 0.f, 0.f};

  const int c0 = t;        // chunk 0 id (16B chunks)
  const int c1 = t + 256;  // chunk 1 id

  for (int kk = 0; kk < K; kk += 32) {
    __syncthreads();
    // stage A tile [128][32] and B tile [128][32] (linear LDS, wave-uniform base + lane*16)
    gload_lds16(A + (size_t)(bm * 128 + (c0 >> 2)) * K + kk + (c0 & 3) * 8,
                As + (size_t)(wave * 64) * 8);
    gload_lds16(A + (size_t)(bm * 128 + (c1 >> 2)) * K + kk + (c1 & 3) * 8,
                As + (size_t)(256 + wave * 64) * 8);
    gload_lds16(Bt + (size_t)(bn * 128 + (c0 >> 2)) * K + kk + (c0 & 3) * 8,
                Bs + (size_t)(wave * 64) * 8);
    gload_lds16(Bt + (size_t)(bn * 128 + (c1 >> 2)) * K + kk + (c1 & 3) * 8,
                Bs + (size_t)(256 + wave * 64) * 8);
    __syncthreads();

    bf16x8 af[4], bfr[4];
#pragma unroll
    for (int f = 0; f < 4; ++f)
      af[f] = *reinterpret_cast<const bf16x8*>(&As[(wm + 16 * f + r) * 32 + g * 8]);
#pragma unroll
    for (int f = 0; f < 4; ++f)
      bfr[f] = *reinterpret_cast<const bf16x8*>(&Bs[(wn + 16 * f + r) * 32 + g * 8]);
#pragma unroll
    for (int fm = 0; fm < 4; ++fm)
#pragma unroll
      for (int fn = 0; fn < 4; ++fn)
        acc[fm][fn] =
            __builtin_amdgcn_mfma_f32_16x16x32_bf16(af[fm], bfr[fn], acc[fm][fn], 0, 0, 0);
  }

  // epilogue: C row = bm*128 + wm + 16*fm + g*4 + j ; col = bn*128 + wn + 16*fn + r
  const int row0 = bm * 128 + wm + g * 4;
  const int col0 = bn * 128 + wn + r;
#pragma unroll
  for (int fn = 0; fn < 4; ++fn) {
    const int col = col0 + 16 * fn;
    const float bv = bias[col];
    if (MODE == 0) {
      const int part = col >> 10, w = col & 1023;
      const int h = w >> 6, dh = w & 63;
      bf16_t* dst = (part == 0) ? Qb : (part == 1) ? Kb : Vb;
#pragma unroll
      for (int fm = 0; fm < 4; ++fm)
#pragma unroll
        for (int j = 0; j < 4; ++j) {
          const int row = row0 + 16 * fm + j;
          const int b = row >> 11, s = row & 2047;
          dst[((size_t)(b * H_ + h) * S_ + s) * DH_ + dh] = (bf16_t)(acc[fm][fn][j] + bv);
        }
    } else {
#pragma unroll
      for (int fm = 0; fm < 4; ++fm)
#pragma unroll
        for (int j = 0; j < 4; ++j) {
          const int row = row0 + 16 * fm + j;
          Out[(size_t)row * N + col] = acc[fm][fn][j] + bv;
        }
    }
  }
}

// ---------------- flash attention, causal; Q/K/V [B,H,S,Dh] bf16 ----------------
// grid: 32 q-tiles x 64 (b,h); block 256 = 4 waves x 16 q-rows; KV tile = 64.
__global__ __launch_bounds__(256) void attn_flash(const bf16_t* __restrict__ Qb,
                                                  const bf16_t* __restrict__ Kb,
                                                  const bf16_t* __restrict__ Vb,
                                                  bf16_t* __restrict__ attnb) {
  __shared__ alignas(16) bf16_t Ks[64 * 72];  // [key][dh] +8 pad
  __shared__ alignas(16) bf16_t Vt[64 * 72];  // [dh][key] +8 pad (transposed)
  __shared__ alignas(16) bf16_t Ps[64 * 72];  // [q local][key] +8 pad (wave-private rows)
  const int t = threadIdx.x;
  const int wave = t >> 6, lane = t & 63;
  const int r = lane & 15, g = lane >> 4;
  const int qt = blockIdx.x & 31, bh = blockIdx.x >> 5;
  const size_t base = (size_t)bh * S_ * DH_;

  // Q fragments in registers (A-operand: row = r, k(dh) = 32*ks + 8*g + j)
  const int qrow = qt * 64 + wave * 16 + r;
  bf16x8 qf[2];
  qf[0] = *reinterpret_cast<const bf16x8*>(Qb + base + (size_t)qrow * DH_ + g * 8);
  qf[1] = *reinterpret_cast<const bf16x8*>(Qb + base + (size_t)qrow * DH_ + 32 + g * 8);

  f32x4 acc[4];
#pragma unroll
  for (int fn = 0; fn < 4; ++fn) acc[fn] = f32x4{0.f, 0.f, 0.f, 0.f};
  float m_j[4], l_j[4];
#pragma unroll
  for (int j = 0; j < 4; ++j) { m_j[j] = -__builtin_inff(); l_j[j] = 0.f; }

  for (int kt = 0; kt <= qt; ++kt) {
    __syncthreads();  // previous tile's reads done
    // stage K [key][dh] and V transposed [dh][key]
#pragma unroll
    for (int i = 0; i < 2; ++i) {
      const int c = i * 256 + t;
      const int row = c >> 3, ch = c & 7;
      const uint4 kv =
          *reinterpret_cast<const uint4*>(Kb + base + (size_t)(kt * 64 + row) * DH_ + ch * 8);
      *reinterpret_cast<uint4*>(&Ks[row * 72 + ch * 8]) = kv;
      const uint4 vv =
          *reinterpret_cast<const uint4*>(Vb + base + (size_t)(kt * 64 + row) * DH_ + ch * 8);
      const bf16_t* vp = reinterpret_cast<const bf16_t*>(&vv);
#pragma unroll
      for (int jj = 0; jj < 8; ++jj) {
        const int j = (jj + (t & 7)) & 7;  // permute to avoid systematic bank conflicts
        Vt[(ch * 8 + j) * 72 + row] = vp[j];
      }
    }
    __syncthreads();

    // S = Q K^T  (16x64 per wave)
    f32x4 sc[4];
#pragma unroll
    for (int fn = 0; fn < 4; ++fn) sc[fn] = f32x4{0.f, 0.f, 0.f, 0.f};
#pragma unroll
    for (int fn = 0; fn < 4; ++fn) {
      const bf16x8 kb0 = *reinterpret_cast<const bf16x8*>(&Ks[(16 * fn + r) * 72 + g * 8]);
      sc[fn] = __builtin_amdgcn_mfma_f32_16x16x32_bf16(qf[0], kb0, sc[fn], 0, 0, 0);
      const bf16x8 kb1 = *reinterpret_cast<const bf16x8*>(&Ks[(16 * fn + r) * 72 + 32 + g * 8]);
      sc[fn] = __builtin_amdgcn_mfma_f32_16x16x32_bf16(qf[1], kb1, sc[fn], 0, 0, 0);
    }

    // scale + causal mask (diag tile only)
    const bool diag = (kt == qt);
#pragma unroll
    for (int fn = 0; fn < 4; ++fn)
#pragma unroll
      for (int j = 0; j < 4; ++j) {
        float v = sc[fn][j] * 0.125f;  // 1/sqrt(64)
        if (diag && (16 * fn + r > wave * 16 + g * 4 + j)) v = -1e30f;
        sc[fn][j] = v;
      }

    // online softmax per row (row = g*4 + j within wave's 16 rows)
    float p[4][4], fac[4];
#pragma unroll
    for (int j = 0; j < 4; ++j) {
      float mx = fmaxf(fmaxf(sc[0][j], sc[1][j]), fmaxf(sc[2][j], sc[3][j]));
#pragma unroll
      for (int off = 1; off < 16; off <<= 1) mx = fmaxf(mx, __shfl_xor(mx, off));
      const float mnew = fmaxf(m_j[j], mx);
      fac[j] = __expf(m_j[j] - mnew);
      float s0 = 0.f;
#pragma unroll
      for (int fn = 0; fn < 4; ++fn) {
        p[fn][j] = __expf(sc[fn][j] - mnew);
        s0 += p[fn][j];
      }
#pragma unroll
      for (int off = 1; off < 16; off <<= 1) s0 += __shfl_xor(s0, off);
      l_j[j] = l_j[j] * fac[j] + s0;
      m_j[j] = mnew;
    }

    // rescale O, write P (bf16) to wave-private LDS rows for transpose
#pragma unroll
    for (int fn = 0; fn < 4; ++fn)
#pragma unroll
      for (int j = 0; j < 4; ++j) {
        acc[fn][j] *= fac[j];
        Ps[(wave * 16 + g * 4 + j) * 72 + 16 * fn + r] = (bf16_t)p[fn][j];
      }

    // O += P V   (A-frag: P[q=r][key=32*ks+8*g+j], B-frag: Vt[dh][key])
#pragma unroll
    for (int ks = 0; ks < 2; ++ks) {
      const bf16x8 pa =
          *reinterpret_cast<const bf16x8*>(&Ps[(wave * 16 + r) * 72 + ks * 32 + g * 8]);
#pragma unroll
      for (int fn = 0; fn < 4; ++fn) {
        const bf16x8 vb =
            *reinterpret_cast<const bf16x8*>(&Vt[(16 * fn + r) * 72 + ks * 32 + g * 8]);
        acc[fn] = __builtin_amdgcn_mfma_f32_16x16x32_bf16(pa, vb, acc[fn], 0, 0, 0);
      }
    }
  }

  // merged-heads output [B,S,D] bf16
  const int b = bh >> 4, h = bh & 15;
#pragma unroll
  for (int j = 0; j < 4; ++j) {
    const float inv = 1.0f / l_j[j];
    const int s = qt * 64 + wave * 16 + g * 4 + j;
#pragma unroll
    for (int fn = 0; fn < 4; ++fn)
      attnb[((size_t)b * S_ + s) * D_ + h * DH_ + 16 * fn + r] = (bf16_t)(acc[fn][j] * inv);
  }
}

extern "C" void kernel_launch(void* const* d_in, const int* in_sizes, int n_in, void* d_out,
                              int out_size, void* d_ws, size_t ws_size, hipStream_t stream) {
  const float* x = (const float*)d_in[0];      // [4,2048,1024]
  const float* wqkv = (const float*)d_in[1];   // [1024,3072]
  const float* bqkv = (const float*)d_in[2];   // [3072]
  const float* wproj = (const float*)d_in[3];  // [1024,1024]
  const float* bproj = (const float*)d_in[4];  // [1024]
  float* out = (float*)d_out;                  // [4,2048,1024]
  char* ws = (char*)d_ws;

  bf16_t* xb = (bf16_t*)(ws);                    // 16 MiB  [8192][1024]
  bf16_t* wqkvT = (bf16_t*)(ws + 16777216);      // 6 MiB   [3072][1024]
  bf16_t* wprojT = (bf16_t*)(ws + 23068672);     // 2 MiB   [1024][1024]
  bf16_t* Qb = (bf16_t*)(ws + 25165824);         // 16 MiB  [B,H,S,Dh]
  bf16_t* Kb = (bf16_t*)(ws + 41943040);         // 16 MiB
  bf16_t* Vb = (bf16_t*)(ws + 58720256);         // 16 MiB
  bf16_t* attnb = (bf16_t*)(ws + 75497472);      // 16 MiB  [8192][1024]

  cast_f32_to_bf16<<<8192, 256, 0, stream>>>(x, xb, (8192 * 1024) / 4);
  transpose_cast<<<dim3(96, 32), 256, 0, stream>>>(wqkv, wqkvT, 1024, 3072);
  transpose_cast<<<dim3(32, 32), 256, 0, stream>>>(wproj, wprojT, 1024, 1024);
  gemm_bf16_128<0><<<dim3(64, 24), 256, 0, stream>>>(xb, wqkvT, bqkv, Qb, Kb, Vb, nullptr,
                                                     8192, 3072, 1024);
  attn_flash<<<2048, 256, 0, stream>>>(Qb, Kb, Vb, attnb);
  gemm_bf16_128<1><<<dim3(64, 8), 256, 0, stream>>>(attnb, wprojT, bproj, nullptr, nullptr,
                                                    nullptr, out, 8192, 1024, 1024);
}

// Round 3
// 296.716 us; speedup vs baseline: 1.7790x; 1.7790x over previous
//
#include <hip/hip_runtime.h>
#include <hip/hip_bf16.h>
#include <stdint.h>

typedef __bf16 bf16_t;
typedef __bf16 bf16x8 __attribute__((ext_vector_type(8)));
typedef __bf16 bf16x4 __attribute__((ext_vector_type(4)));
typedef float f32x4 __attribute__((ext_vector_type(4)));
typedef float f32x16 __attribute__((ext_vector_type(16)));

#define B_ 4
#define S_ 2048
#define D_ 1024
#define H_ 16
#define DH_ 64

// ---------------- cast: fp32 -> bf16 ----------------
__global__ __launch_bounds__(256) void cast_f32_to_bf16(const float* __restrict__ in,
                                                        bf16_t* __restrict__ out, int n4) {
  int i = blockIdx.x * 256 + threadIdx.x;
  if (i < n4) {
    const float4 v = reinterpret_cast<const float4*>(in)[i];
    bf16x4 o;
    o[0] = (bf16_t)v.x; o[1] = (bf16_t)v.y; o[2] = (bf16_t)v.z; o[3] = (bf16_t)v.w;
    reinterpret_cast<bf16x4*>(out)[i] = o;
  }
}

// ---------------- transpose-cast: in [K][N] fp32 -> out [N][K] bf16 ----------------
__global__ __launch_bounds__(256) void transpose_cast(const float* __restrict__ in,
                                                      bf16_t* __restrict__ out, int K, int N) {
  __shared__ float tile[32][33];
  const int bx = blockIdx.x * 32;
  const int by = blockIdx.y * 32;
  const int tx = threadIdx.x & 31;
  const int ty = threadIdx.x >> 5;
#pragma unroll
  for (int i = 0; i < 32; i += 8)
    tile[ty + i][tx] = in[(size_t)(by + ty + i) * N + bx + tx];
  __syncthreads();
#pragma unroll
  for (int i = 0; i < 32; i += 8)
    out[(size_t)(bx + ty + i) * K + by + tx] = (bf16_t)tile[tx][ty + i];
}

// ---------------- async global->LDS 16B ----------------
__device__ __forceinline__ void gload_lds16(const bf16_t* g, bf16_t* l) {
  __builtin_amdgcn_global_load_lds((const __attribute__((address_space(1))) void*)g,
                                   (__attribute__((address_space(3))) void*)l, 16, 0, 0);
}

// ---------------- bf16 GEMM, 128x128 tile, BK=32 (m97 structure) ----------------
// MODE 0: QKV epilogue -> Q,K [bh][s][dh]; V^T [bh][dh][s] (plain layouts).
// MODE 1: proj epilogue -> fp32 Out[M][N] with bias.
template <int MODE>
__global__ __launch_bounds__(256) void gemm_bf16_128(
    const bf16_t* __restrict__ A, const bf16_t* __restrict__ Bt,
    const float* __restrict__ bias,
    bf16_t* __restrict__ Qb, bf16_t* __restrict__ Kb, bf16_t* __restrict__ Vtb,
    float* __restrict__ Out, int M, int N, int K) {
  __shared__ alignas(16) bf16_t As[128 * 32];
  __shared__ alignas(16) bf16_t Bs[128 * 32];
  const int t = threadIdx.x;
  const int wave = t >> 6, lane = t & 63;
  const int r = lane & 15, g = lane >> 4;
  const int bm = blockIdx.x, bn = blockIdx.y;
  const int wm = (wave & 1) * 64, wn = (wave >> 1) * 64;

  f32x4 acc[4][4];
#pragma unroll
  for (int i = 0; i < 4; ++i)
#pragma unroll
    for (int j = 0; j < 4; ++j) acc[i][j] = f32x4{0.f, 0.f, 0.f, 0.f};

  const int c0 = t;
  const int c1 = t + 256;

  for (int kk = 0; kk < K; kk += 32) {
    __syncthreads();
    gload_lds16(A + (size_t)(bm * 128 + (c0 >> 2)) * K + kk + (c0 & 3) * 8,
                As + (size_t)(wave * 64) * 8);
    gload_lds16(A + (size_t)(bm * 128 + (c1 >> 2)) * K + kk + (c1 & 3) * 8,
                As + (size_t)(256 + wave * 64) * 8);
    gload_lds16(Bt + (size_t)(bn * 128 + (c0 >> 2)) * K + kk + (c0 & 3) * 8,
                Bs + (size_t)(wave * 64) * 8);
    gload_lds16(Bt + (size_t)(bn * 128 + (c1 >> 2)) * K + kk + (c1 & 3) * 8,
                Bs + (size_t)(256 + wave * 64) * 8);
    __syncthreads();

    bf16x8 af[4], bfr[4];
#pragma unroll
    for (int f = 0; f < 4; ++f)
      af[f] = *reinterpret_cast<const bf16x8*>(&As[(wm + 16 * f + r) * 32 + g * 8]);
#pragma unroll
    for (int f = 0; f < 4; ++f)
      bfr[f] = *reinterpret_cast<const bf16x8*>(&Bs[(wn + 16 * f + r) * 32 + g * 8]);
#pragma unroll
    for (int fm = 0; fm < 4; ++fm)
#pragma unroll
      for (int fn = 0; fn < 4; ++fn)
        acc[fm][fn] =
            __builtin_amdgcn_mfma_f32_16x16x32_bf16(af[fm], bfr[fn], acc[fm][fn], 0, 0, 0);
  }

  const int row0 = bm * 128 + wm + g * 4;
  const int col0 = bn * 128 + wn + r;
#pragma unroll
  for (int fn = 0; fn < 4; ++fn) {
    const int col = col0 + 16 * fn;
    const float bv = bias[col];
    if (MODE == 0) {
      const int part = col >> 10, w = col & 1023;
      const int h = w >> 6, dh = w & 63;
#pragma unroll
      for (int fm = 0; fm < 4; ++fm)
#pragma unroll
        for (int j = 0; j < 4; ++j) {
          const int row = row0 + 16 * fm + j;
          const int b = row >> 11, s = row & 2047;
          const float val = acc[fm][fn][j] + bv;
          const size_t bhb = (size_t)(b * H_ + h);
          if (part == 0) {
            Qb[(bhb * S_ + s) * DH_ + dh] = (bf16_t)val;
          } else if (part == 1) {
            Kb[(bhb * S_ + s) * DH_ + dh] = (bf16_t)val;
          } else {
            Vtb[(bhb * DH_ + dh) * S_ + s] = (bf16_t)val;
          }
        }
    } else {
#pragma unroll
      for (int fm = 0; fm < 4; ++fm)
#pragma unroll
        for (int j = 0; j < 4; ++j) {
          const int row = row0 + 16 * fm + j;
          Out[(size_t)row * N + col] = acc[fm][fn][j] + bv;
        }
    }
  }
}

// ---------------- flash attention v3: swapped QK^T, in-lane softmax ----------------
// grid (64 bh, 8 pairs); block 256 = 4 waves x 32 q-rows; passes {pair, 15-pair}
// -> every block exactly 36 KV tiles of 64 keys.
__global__ __launch_bounds__(256) void attn_flash3(const bf16_t* __restrict__ Qb,
                                                   const bf16_t* __restrict__ Kb,
                                                   const bf16_t* __restrict__ Vtb,
                                                   bf16_t* __restrict__ attnb) {
  __shared__ alignas(16) bf16_t Kl[2][64 * 64];  // [key][dh], 16B-chunk ^= (key&7)
  __shared__ alignas(16) bf16_t Vl[2][64 * 64];  // [dh][key], 16B-chunk ^= (dh&7)
  __shared__ alignas(16) bf16_t Ps[4][32 * 72];  // wave-private P[q][key] (reused for O)
  const int t = threadIdx.x, wave = t >> 6, lane = t & 63;
  const int q5 = lane & 31, hi = lane >> 5;
  const int bh = blockIdx.x, pair = blockIdx.y;
  const size_t kqbase = (size_t)bh * (S_ * DH_);
  const size_t vbase = (size_t)bh * (DH_ * S_);
  const int b = bh >> 4, h = bh & 15;
  const float SC = 0.18033688f;  // 0.125 * log2(e); softmax in exp2 domain

  // staging: 256 threads x 2 chunks of 16B for each of K,V (64 rows x 8 chunks)
  const int r0s = t >> 3, ch0 = t & 7;
  const int r1s = (t + 256) >> 3, ch1 = t & 7;  // (t+256)&7 == t&7
  const int lk0 = r0s * 64 + ((ch0 ^ (r0s & 7)) << 3);
  const int lk1 = r1s * 64 + ((ch1 ^ (r1s & 7)) << 3);

  for (int pass = 0; pass < 2; ++pass) {
    const int qb = pass ? 15 - pair : pair;
    const int qbase = qb * 128;
    const int wq = qbase + wave * 32;
    const int qg = wq + q5;          // this lane's q row (as MFMA column)
    const int ktmax = 2 * qb + 1;    // block's last KV tile
    const int ktw = wq >> 6;         // this wave's last (and only masked) KV tile

    // Q fragments (B-operand): qf[d][j] = Q[qg][16d + 8hi + j]
    bf16x8 qf[4];
#pragma unroll
    for (int d = 0; d < 4; ++d)
      qf[d] = *reinterpret_cast<const bf16x8*>(Qb + kqbase + (size_t)qg * DH_ + d * 16 + hi * 8);

    f32x16 oa, ob;  // O^T: col q=q5, row dh=crow(r,hi) (+32 for ob)
#pragma unroll
    for (int r = 0; r < 16; ++r) { oa[r] = 0.f; ob[r] = 0.f; }
    float mrun = -1e30f, lrun = 0.f;

    {  // prologue: stage tile 0
      const bf16_t* kg = Kb + kqbase;
      const bf16_t* vg = Vtb + vbase;
      const uint4 a = *reinterpret_cast<const uint4*>(kg + r0s * DH_ + ch0 * 8);
      const uint4 bq = *reinterpret_cast<const uint4*>(kg + r1s * DH_ + ch1 * 8);
      const uint4 c = *reinterpret_cast<const uint4*>(vg + (size_t)r0s * S_ + ch0 * 8);
      const uint4 d = *reinterpret_cast<const uint4*>(vg + (size_t)r1s * S_ + ch1 * 8);
      *reinterpret_cast<uint4*>(&Kl[0][lk0]) = a;
      *reinterpret_cast<uint4*>(&Kl[0][lk1]) = bq;
      *reinterpret_cast<uint4*>(&Vl[0][lk0]) = c;
      *reinterpret_cast<uint4*>(&Vl[0][lk1]) = d;
      __syncthreads();
    }

    int cur = 0;
    for (int kt = 0; kt <= ktmax; ++kt) {
      uint4 ra, rb, rc, rd;
      const bool more = kt < ktmax;
      if (more) {  // T14: issue next-tile loads before compute
        const bf16_t* kg = Kb + kqbase + (size_t)(kt + 1) * (64 * DH_);
        const bf16_t* vg = Vtb + vbase + (kt + 1) * 64;
        ra = *reinterpret_cast<const uint4*>(kg + r0s * DH_ + ch0 * 8);
        rb = *reinterpret_cast<const uint4*>(kg + r1s * DH_ + ch1 * 8);
        rc = *reinterpret_cast<const uint4*>(vg + (size_t)r0s * S_ + ch0 * 8);
        rd = *reinterpret_cast<const uint4*>(vg + (size_t)r1s * S_ + ch1 * 8);
      }

      if (kt <= ktw) {
        const bf16_t* KL = &Kl[cur][0];
        const bf16_t* VL = &Vl[cur][0];
        // ---- S^T = K Q^T: s0 keys 0..31, s1 keys 32..63; col = q ----
        f32x16 s0, s1;
#pragma unroll
        for (int r = 0; r < 16; ++r) { s0[r] = 0.f; s1[r] = 0.f; }
#pragma unroll
        for (int d = 0; d < 4; ++d) {
          const int cx = ((2 * d + hi) ^ (q5 & 7)) << 3;
          const bf16x8 kfa = *reinterpret_cast<const bf16x8*>(&KL[q5 * 64 + cx]);
          s0 = __builtin_amdgcn_mfma_f32_32x32x16_bf16(kfa, qf[d], s0, 0, 0, 0);
          const bf16x8 kfb = *reinterpret_cast<const bf16x8*>(&KL[(32 + q5) * 64 + cx]);
          s1 = __builtin_amdgcn_mfma_f32_32x32x16_bf16(kfb, qf[d], s1, 0, 0, 0);
        }

        float p0[16], p1[16];
#pragma unroll
        for (int r = 0; r < 16; ++r) { p0[r] = s0[r] * SC; p1[r] = s1[r] * SC; }
        if (kt == ktw) {  // causal mask (diag tile only)
#pragma unroll
          for (int r = 0; r < 16; ++r) {
            const int crow = (r & 3) + 8 * (r >> 2) + 4 * hi;
            if (kt * 64 + crow > qg) p0[r] = -1e30f;
            if (kt * 64 + 32 + crow > qg) p1[r] = -1e30f;
          }
        }

        // ---- in-lane row max over all 32 own values, then one cross-half shfl ----
        float t8[8];
#pragma unroll
        for (int i = 0; i < 8; ++i)
          t8[i] = fmaxf(fmaxf(p0[i], p0[i + 8]), fmaxf(p1[i], p1[i + 8]));
        float vm = fmaxf(fmaxf(fmaxf(t8[0], t8[1]), fmaxf(t8[2], t8[3])),
                         fmaxf(fmaxf(t8[4], t8[5]), fmaxf(t8[6], t8[7])));
        vm = fmaxf(vm, __shfl_xor(vm, 32));
        const float mnew = fmaxf(mrun, vm);
        const float fac = exp2f(mrun - mnew);
#pragma unroll
        for (int r = 0; r < 16; ++r) {
          p0[r] = exp2f(p0[r] - mnew);
          p1[r] = exp2f(p1[r] - mnew);
        }
        float s8[8];
#pragma unroll
        for (int i = 0; i < 8; ++i) s8[i] = (p0[i] + p0[i + 8]) + (p1[i] + p1[i + 8]);
        float sum = ((s8[0] + s8[1]) + (s8[2] + s8[3])) + ((s8[4] + s8[5]) + (s8[6] + s8[7]));
        sum += __shfl_xor(sum, 32);
        lrun = lrun * fac + sum;
        mrun = mnew;
#pragma unroll
        for (int r = 0; r < 16; ++r) { oa[r] *= fac; ob[r] *= fac; }

        // ---- P -> wave-private LDS (packed dword stores), P[q][key] ----
        bf16_t* PSW = &Ps[wave][0];
#pragma unroll
        for (int r = 0; r < 16; r += 2) {
          const int crow = (r & 3) + 8 * (r >> 2) + 4 * hi;  // even; r+1 -> crow+1
          union { bf16_t hh[2]; unsigned u; } ua, ub;
          ua.hh[0] = (bf16_t)p0[r]; ua.hh[1] = (bf16_t)p0[r + 1];
          ub.hh[0] = (bf16_t)p1[r]; ub.hh[1] = (bf16_t)p1[r + 1];
          *reinterpret_cast<unsigned*>(&PSW[q5 * 72 + crow]) = ua.u;
          *reinterpret_cast<unsigned*>(&PSW[q5 * 72 + 32 + crow]) = ub.u;
        }

        // ---- O^T += V^T P^T : A = V^T rows(dh), B-frag read from Ps ----
#pragma unroll
        for (int tt = 0; tt < 4; ++tt) {
          const bf16x8 pb = *reinterpret_cast<const bf16x8*>(&PSW[q5 * 72 + tt * 16 + hi * 8]);
          const int cx = ((2 * tt + hi) ^ (q5 & 7)) << 3;
          const bf16x8 va = *reinterpret_cast<const bf16x8*>(&VL[q5 * 64 + cx]);
          oa = __builtin_amdgcn_mfma_f32_32x32x16_bf16(va, pb, oa, 0, 0, 0);
          const bf16x8 vb = *reinterpret_cast<const bf16x8*>(&VL[(32 + q5) * 64 + cx]);
          ob = __builtin_amdgcn_mfma_f32_32x32x16_bf16(vb, pb, ob, 0, 0, 0);
        }
      }

      if (more) {  // T14: write-late into the other buffer
        *reinterpret_cast<uint4*>(&Kl[cur ^ 1][lk0]) = ra;
        *reinterpret_cast<uint4*>(&Kl[cur ^ 1][lk1]) = rb;
        *reinterpret_cast<uint4*>(&Vl[cur ^ 1][lk0]) = rc;
        *reinterpret_cast<uint4*>(&Vl[cur ^ 1][lk1]) = rd;
      }
      __syncthreads();
      cur ^= 1;
    }

    // ---- epilogue: normalize, transpose via wave-private LDS, cooperative store ----
    const float inv = 1.0f / lrun;
    bf16_t* PSW = &Ps[wave][0];
#pragma unroll
    for (int r = 0; r < 16; ++r) {
      const int crow = (r & 3) + 8 * (r >> 2) + 4 * hi;
      PSW[q5 * 72 + crow] = (bf16_t)(oa[r] * inv);
      PSW[q5 * 72 + 32 + crow] = (bf16_t)(ob[r] * inv);
    }
    // wave-private readback (compiler inserts lgkmcnt); 8 chunks/row coalesced
#pragma unroll
    for (int i = 0; i < 4; ++i) {
      const int cc = i * 64 + lane;
      const int row = cc >> 3, ch = cc & 7;
      const bf16x8 v = *reinterpret_cast<const bf16x8*>(&PSW[row * 72 + ch * 8]);
      *reinterpret_cast<bf16x8*>(attnb + ((size_t)(b * S_ + wq + row)) * D_ + h * DH_ + ch * 8) = v;
    }
  }
}

extern "C" void kernel_launch(void* const* d_in, const int* in_sizes, int n_in, void* d_out,
                              int out_size, void* d_ws, size_t ws_size, hipStream_t stream) {
  const float* x = (const float*)d_in[0];      // [4,2048,1024]
  const float* wqkv = (const float*)d_in[1];   // [1024,3072]
  const float* bqkv = (const float*)d_in[2];   // [3072]
  const float* wproj = (const float*)d_in[3];  // [1024,1024]
  const float* bproj = (const float*)d_in[4];  // [1024]
  float* out = (float*)d_out;                  // [4,2048,1024]
  char* ws = (char*)d_ws;

  bf16_t* xb = (bf16_t*)(ws);                 // 16 MiB [8192][1024]
  bf16_t* wqkvT = (bf16_t*)(ws + 16777216);   // 6 MiB  [3072][1024]
  bf16_t* wprojT = (bf16_t*)(ws + 23068672);  // 2 MiB  [1024][1024]
  bf16_t* Qb = (bf16_t*)(ws + 25165824);      // 16 MiB [B,H,S,Dh]
  bf16_t* Kb = (bf16_t*)(ws + 41943040);      // 16 MiB [B,H,S,Dh]
  bf16_t* Vtb = (bf16_t*)(ws + 58720256);     // 16 MiB [B,H,Dh,S]
  bf16_t* attnb = (bf16_t*)(ws + 75497472);   // 16 MiB [8192][1024]

  cast_f32_to_bf16<<<8192, 256, 0, stream>>>(x, xb, (8192 * 1024) / 4);
  transpose_cast<<<dim3(96, 32), 256, 0, stream>>>(wqkv, wqkvT, 1024, 3072);
  transpose_cast<<<dim3(32, 32), 256, 0, stream>>>(wproj, wprojT, 1024, 1024);
  gemm_bf16_128<0><<<dim3(64, 24), 256, 0, stream>>>(xb, wqkvT, bqkv, Qb, Kb, Vtb, nullptr,
                                                     8192, 3072, 1024);
  attn_flash3<<<dim3(64, 8), 256, 0, stream>>>(Qb, Kb, Vtb, attnb);
  gemm_bf16_128<1><<<dim3(64, 8), 256, 0, stream>>>(attnb, wprojT, bproj, nullptr, nullptr,
                                                    nullptr, out, 8192, 1024, 1024);
}

// Round 4
// 279.423 us; speedup vs baseline: 1.8891x; 1.0619x over previous
//
#include <hip/hip_runtime.h>
#include <hip/hip_bf16.h>
#include <stdint.h>

typedef __bf16 bf16_t;
typedef __bf16 bf16x8 __attribute__((ext_vector_type(8)));
typedef __bf16 bf16x4 __attribute__((ext_vector_type(4)));
typedef float f32x4 __attribute__((ext_vector_type(4)));
typedef float f32x16 __attribute__((ext_vector_type(16)));

#define B_ 4
#define S_ 2048
#define D_ 1024
#define H_ 16
#define DH_ 64

// ---------------- cast: fp32 -> bf16 ----------------
__global__ __launch_bounds__(256) void cast_f32_to_bf16(const float* __restrict__ in,
                                                        bf16_t* __restrict__ out, int n4) {
  int i = blockIdx.x * 256 + threadIdx.x;
  if (i < n4) {
    const float4 v = reinterpret_cast<const float4*>(in)[i];
    bf16x4 o;
    o[0] = (bf16_t)v.x; o[1] = (bf16_t)v.y; o[2] = (bf16_t)v.z; o[3] = (bf16_t)v.w;
    reinterpret_cast<bf16x4*>(out)[i] = o;
  }
}

// ---------------- transpose-cast: in [K][N] fp32 -> out [N][K] bf16 ----------------
__global__ __launch_bounds__(256) void transpose_cast(const float* __restrict__ in,
                                                      bf16_t* __restrict__ out, int K, int N) {
  __shared__ float tile[32][33];
  const int bx = blockIdx.x * 32;
  const int by = blockIdx.y * 32;
  const int tx = threadIdx.x & 31;
  const int ty = threadIdx.x >> 5;
#pragma unroll
  for (int i = 0; i < 32; i += 8)
    tile[ty + i][tx] = in[(size_t)(by + ty + i) * N + bx + tx];
  __syncthreads();
#pragma unroll
  for (int i = 0; i < 32; i += 8)
    out[(size_t)(bx + ty + i) * K + by + tx] = (bf16_t)tile[tx][ty + i];
}

// ---------------- async global->LDS 16B ----------------
__device__ __forceinline__ void gload_lds16(const bf16_t* g, bf16_t* l) {
  __builtin_amdgcn_global_load_lds((const __attribute__((address_space(1))) void*)g,
                                   (__attribute__((address_space(3))) void*)l, 16, 0, 0);
}

// ---------------- bf16 GEMM, 128x128 tile, BK=32 (m97 structure) ----------------
// MODE 0: QKV epilogue -> Q,K [bh][s][dh]; V^T [bh][dh][s] (plain layouts).
// MODE 1: proj epilogue -> fp32 Out[M][N] with bias.
template <int MODE>
__global__ __launch_bounds__(256) void gemm_bf16_128(
    const bf16_t* __restrict__ A, const bf16_t* __restrict__ Bt,
    const float* __restrict__ bias,
    bf16_t* __restrict__ Qb, bf16_t* __restrict__ Kb, bf16_t* __restrict__ Vtb,
    float* __restrict__ Out, int M, int N, int K) {
  __shared__ alignas(16) bf16_t As[128 * 32];
  __shared__ alignas(16) bf16_t Bs[128 * 32];
  const int t = threadIdx.x;
  const int wave = t >> 6, lane = t & 63;
  const int r = lane & 15, g = lane >> 4;
  const int bm = blockIdx.x, bn = blockIdx.y;
  const int wm = (wave & 1) * 64, wn = (wave >> 1) * 64;

  f32x4 acc[4][4];
#pragma unroll
  for (int i = 0; i < 4; ++i)
#pragma unroll
    for (int j = 0; j < 4; ++j) acc[i][j] = f32x4{0.f, 0.f, 0.f, 0.f};

  const int c0 = t;
  const int c1 = t + 256;

  for (int kk = 0; kk < K; kk += 32) {
    __syncthreads();
    gload_lds16(A + (size_t)(bm * 128 + (c0 >> 2)) * K + kk + (c0 & 3) * 8,
                As + (size_t)(wave * 64) * 8);
    gload_lds16(A + (size_t)(bm * 128 + (c1 >> 2)) * K + kk + (c1 & 3) * 8,
                As + (size_t)(256 + wave * 64) * 8);
    gload_lds16(Bt + (size_t)(bn * 128 + (c0 >> 2)) * K + kk + (c0 & 3) * 8,
                Bs + (size_t)(wave * 64) * 8);
    gload_lds16(Bt + (size_t)(bn * 128 + (c1 >> 2)) * K + kk + (c1 & 3) * 8,
                Bs + (size_t)(256 + wave * 64) * 8);
    __syncthreads();

    bf16x8 af[4], bfr[4];
#pragma unroll
    for (int f = 0; f < 4; ++f)
      af[f] = *reinterpret_cast<const bf16x8*>(&As[(wm + 16 * f + r) * 32 + g * 8]);
#pragma unroll
    for (int f = 0; f < 4; ++f)
      bfr[f] = *reinterpret_cast<const bf16x8*>(&Bs[(wn + 16 * f + r) * 32 + g * 8]);
#pragma unroll
    for (int fm = 0; fm < 4; ++fm)
#pragma unroll
      for (int fn = 0; fn < 4; ++fn)
        acc[fm][fn] =
            __builtin_amdgcn_mfma_f32_16x16x32_bf16(af[fm], bfr[fn], acc[fm][fn], 0, 0, 0);
  }

  const int row0 = bm * 128 + wm + g * 4;
  const int col0 = bn * 128 + wn + r;
#pragma unroll
  for (int fn = 0; fn < 4; ++fn) {
    const int col = col0 + 16 * fn;
    const float bv = bias[col];
    if (MODE == 0) {
      const int part = col >> 10, w = col & 1023;
      const int h = w >> 6, dh = w & 63;
#pragma unroll
      for (int fm = 0; fm < 4; ++fm) {
        const int row = row0 + 16 * fm;  // multiple of 4; j-rows share b
        const int b = row >> 11, s = row & 2047;
        const size_t bhb = (size_t)(b * H_ + h);
        if (part == 2) {
          // V^T: 4 consecutive s -> one 8B store
          union { bf16_t hh[4]; uint2 u; } pk;
#pragma unroll
          for (int j = 0; j < 4; ++j) pk.hh[j] = (bf16_t)(acc[fm][fn][j] + bv);
          *reinterpret_cast<uint2*>(&Vtb[(bhb * DH_ + dh) * S_ + s]) = pk.u;
        } else {
          bf16_t* dst = (part == 0) ? Qb : Kb;
#pragma unroll
          for (int j = 0; j < 4; ++j)
            dst[(bhb * S_ + s + j) * DH_ + dh] = (bf16_t)(acc[fm][fn][j] + bv);
        }
      }
    } else {
#pragma unroll
      for (int fm = 0; fm < 4; ++fm)
#pragma unroll
        for (int j = 0; j < 4; ++j) {
          const int row = row0 + 16 * fm + j;
          Out[(size_t)row * N + col] = acc[fm][fn][j] + bv;
        }
    }
  }
}

// ---------------- flash attention v4: swapped QK^T, in-lane softmax, defer-max ----
// grid (64 bh, 16 qb-desc); block 256 = 4 waves x 32 q-rows; qb = 15 - by
// (heaviest first, LPT packing). Per block: 2qb+2 KV tiles of 64 keys.
__global__ __launch_bounds__(256) void attn_flash4(const bf16_t* __restrict__ Qb,
                                                   const bf16_t* __restrict__ Kb,
                                                   const bf16_t* __restrict__ Vtb,
                                                   bf16_t* __restrict__ attnb) {
  __shared__ alignas(16) bf16_t Kl[2][64 * 64];  // [key][dh], 16B-chunk ^= (key&7)
  __shared__ alignas(16) bf16_t Vl[2][64 * 64];  // [dh][key], 16B-chunk ^= (dh&7)
  __shared__ alignas(16) bf16_t Ps[4][32 * 72];  // wave-private P[q][key] (reused for O)
  const int t = threadIdx.x, wave = t >> 6, lane = t & 63;
  const int q5 = lane & 31, hi = lane >> 5;
  const int bh = blockIdx.x, qb = 15 - (int)blockIdx.y;
  const size_t kqbase = (size_t)bh * (S_ * DH_);
  const size_t vbase = (size_t)bh * (DH_ * S_);
  const int b = bh >> 4, h = bh & 15;
  const float SC = 0.18033688f;  // 0.125 * log2(e); softmax in exp2 domain

  // staging: 256 threads x 2 chunks of 16B for each of K,V (64 rows x 8 chunks)
  const int r0s = t >> 3, ch0 = t & 7;
  const int r1s = (t + 256) >> 3, ch1 = t & 7;
  const int lk0 = r0s * 64 + ((ch0 ^ (r0s & 7)) << 3);
  const int lk1 = r1s * 64 + ((ch1 ^ (r1s & 7)) << 3);

  const int qbase = qb * 128;
  const int wq = qbase + wave * 32;
  const int qg = wq + q5;        // this lane's q row (as MFMA column)
  const int ktmax = 2 * qb + 1;  // block's last KV tile
  const int ktw = wq >> 6;       // this wave's last (and only masked) KV tile

  // Q fragments (B-operand): qf[d][j] = Q[qg][16d + 8hi + j]
  bf16x8 qf[4];
#pragma unroll
  for (int d = 0; d < 4; ++d)
    qf[d] = *reinterpret_cast<const bf16x8*>(Qb + kqbase + (size_t)qg * DH_ + d * 16 + hi * 8);

  f32x16 oa, ob;  // O^T: col q=q5, row dh=crow(r,hi) (+32 for ob)
#pragma unroll
  for (int r = 0; r < 16; ++r) { oa[r] = 0.f; ob[r] = 0.f; }
  float mrun = -1e30f, lrun = 0.f;

  {  // prologue: stage tile 0
    const bf16_t* kg = Kb + kqbase;
    const bf16_t* vg = Vtb + vbase;
    const uint4 a = *reinterpret_cast<const uint4*>(kg + r0s * DH_ + ch0 * 8);
    const uint4 bq = *reinterpret_cast<const uint4*>(kg + r1s * DH_ + ch1 * 8);
    const uint4 c = *reinterpret_cast<const uint4*>(vg + (size_t)r0s * S_ + ch0 * 8);
    const uint4 d = *reinterpret_cast<const uint4*>(vg + (size_t)r1s * S_ + ch1 * 8);
    *reinterpret_cast<uint4*>(&Kl[0][lk0]) = a;
    *reinterpret_cast<uint4*>(&Kl[0][lk1]) = bq;
    *reinterpret_cast<uint4*>(&Vl[0][lk0]) = c;
    *reinterpret_cast<uint4*>(&Vl[0][lk1]) = d;
    __syncthreads();
  }

  int cur = 0;
  for (int kt = 0; kt <= ktmax; ++kt) {
    uint4 ra, rb, rc, rd;
    const bool more = kt < ktmax;
    if (more) {  // T14: issue next-tile loads before compute
      const bf16_t* kg = Kb + kqbase + (size_t)(kt + 1) * (64 * DH_);
      const bf16_t* vg = Vtb + vbase + (kt + 1) * 64;
      ra = *reinterpret_cast<const uint4*>(kg + r0s * DH_ + ch0 * 8);
      rb = *reinterpret_cast<const uint4*>(kg + r1s * DH_ + ch1 * 8);
      rc = *reinterpret_cast<const uint4*>(vg + (size_t)r0s * S_ + ch0 * 8);
      rd = *reinterpret_cast<const uint4*>(vg + (size_t)r1s * S_ + ch1 * 8);
    }

    if (kt <= ktw) {
      const bf16_t* KL = &Kl[cur][0];
      const bf16_t* VL = &Vl[cur][0];
      // ---- S^T = K Q^T: s0 keys 0..31, s1 keys 32..63; col = q ----
      f32x16 s0, s1;
#pragma unroll
      for (int r = 0; r < 16; ++r) { s0[r] = 0.f; s1[r] = 0.f; }
#pragma unroll
      for (int d = 0; d < 4; ++d) {
        const int cx = ((2 * d + hi) ^ (q5 & 7)) << 3;
        const bf16x8 kfa = *reinterpret_cast<const bf16x8*>(&KL[q5 * 64 + cx]);
        s0 = __builtin_amdgcn_mfma_f32_32x32x16_bf16(kfa, qf[d], s0, 0, 0, 0);
        const bf16x8 kfb = *reinterpret_cast<const bf16x8*>(&KL[(32 + q5) * 64 + cx]);
        s1 = __builtin_amdgcn_mfma_f32_32x32x16_bf16(kfb, qf[d], s1, 0, 0, 0);
      }

      if (kt == ktw) {  // causal mask in raw-score domain (diag tile only)
#pragma unroll
        for (int r = 0; r < 16; ++r) {
          const int crow = (r & 3) + 8 * (r >> 2) + 4 * hi;
          if (kt * 64 + crow > qg) s0[r] = -1e30f;
          if (kt * 64 + 32 + crow > qg) s1[r] = -1e30f;
        }
      }

      // ---- in-lane row max (raw domain), one cross-half shfl ----
      float t8[8];
#pragma unroll
      for (int i = 0; i < 8; ++i)
        t8[i] = fmaxf(fmaxf(s0[i], s0[i + 8]), fmaxf(s1[i], s1[i + 8]));
      float vm = fmaxf(fmaxf(fmaxf(t8[0], t8[1]), fmaxf(t8[2], t8[3])),
                       fmaxf(fmaxf(t8[4], t8[5]), fmaxf(t8[6], t8[7])));
      vm = fmaxf(vm, __shfl_xor(vm, 32));
      const float vms = vm * SC;  // scaled candidate max

      // ---- T13 defer-max: skip O-rescale when growth <= 8 (P bounded by 2^8) ----
      if (!__all(vms - mrun <= 8.f)) {
        const float mnew = fmaxf(mrun, vms);
        const float fac = exp2f(mrun - mnew);
#pragma unroll
        for (int r = 0; r < 16; ++r) { oa[r] *= fac; ob[r] *= fac; }
        lrun *= fac;
        mrun = mnew;
      }

      float p0[16], p1[16];
#pragma unroll
      for (int r = 0; r < 16; ++r) {
        p0[r] = exp2f(fmaf(s0[r], SC, -mrun));
        p1[r] = exp2f(fmaf(s1[r], SC, -mrun));
      }
      float s8[8];
#pragma unroll
      for (int i = 0; i < 8; ++i) s8[i] = (p0[i] + p0[i + 8]) + (p1[i] + p1[i + 8]);
      float sum = ((s8[0] + s8[1]) + (s8[2] + s8[3])) + ((s8[4] + s8[5]) + (s8[6] + s8[7]));
      sum += __shfl_xor(sum, 32);
      lrun += sum;

      // ---- P -> wave-private LDS (packed dword stores), P[q][key] ----
      bf16_t* PSW = &Ps[wave][0];
#pragma unroll
      for (int r = 0; r < 16; r += 2) {
        const int crow = (r & 3) + 8 * (r >> 2) + 4 * hi;  // even; r+1 -> crow+1
        union { bf16_t hh[2]; unsigned u; } ua, ub;
        ua.hh[0] = (bf16_t)p0[r]; ua.hh[1] = (bf16_t)p0[r + 1];
        ub.hh[0] = (bf16_t)p1[r]; ub.hh[1] = (bf16_t)p1[r + 1];
        *reinterpret_cast<unsigned*>(&PSW[q5 * 72 + crow]) = ua.u;
        *reinterpret_cast<unsigned*>(&PSW[q5 * 72 + 32 + crow]) = ub.u;
      }

      // ---- O^T += V^T P^T : A = V^T rows(dh), B-frag read from Ps ----
#pragma unroll
      for (int tt = 0; tt < 4; ++tt) {
        const bf16x8 pb = *reinterpret_cast<const bf16x8*>(&PSW[q5 * 72 + tt * 16 + hi * 8]);
        const int cx = ((2 * tt + hi) ^ (q5 & 7)) << 3;
        const bf16x8 va = *reinterpret_cast<const bf16x8*>(&VL[q5 * 64 + cx]);
        oa = __builtin_amdgcn_mfma_f32_32x32x16_bf16(va, pb, oa, 0, 0, 0);
        const bf16x8 vb = *reinterpret_cast<const bf16x8*>(&VL[(32 + q5) * 64 + cx]);
        ob = __builtin_amdgcn_mfma_f32_32x32x16_bf16(vb, pb, ob, 0, 0, 0);
      }
    }

    if (more) {  // T14: write-late into the other buffer
      *reinterpret_cast<uint4*>(&Kl[cur ^ 1][lk0]) = ra;
      *reinterpret_cast<uint4*>(&Kl[cur ^ 1][lk1]) = rb;
      *reinterpret_cast<uint4*>(&Vl[cur ^ 1][lk0]) = rc;
      *reinterpret_cast<uint4*>(&Vl[cur ^ 1][lk1]) = rd;
    }
    __syncthreads();
    cur ^= 1;
  }

  // ---- epilogue: normalize, transpose via wave-private LDS, cooperative store ----
  const float inv = 1.0f / lrun;
  bf16_t* PSW = &Ps[wave][0];
#pragma unroll
  for (int r = 0; r < 16; ++r) {
    const int crow = (r & 3) + 8 * (r >> 2) + 4 * hi;
    PSW[q5 * 72 + crow] = (bf16_t)(oa[r] * inv);
    PSW[q5 * 72 + 32 + crow] = (bf16_t)(ob[r] * inv);
  }
#pragma unroll
  for (int i = 0; i < 4; ++i) {
    const int cc = i * 64 + lane;
    const int row = cc >> 3, ch = cc & 7;
    const bf16x8 v = *reinterpret_cast<const bf16x8*>(&PSW[row * 72 + ch * 8]);
    *reinterpret_cast<bf16x8*>(attnb + ((size_t)(b * S_ + wq + row)) * D_ + h * DH_ + ch * 8) = v;
  }
}

extern "C" void kernel_launch(void* const* d_in, const int* in_sizes, int n_in, void* d_out,
                              int out_size, void* d_ws, size_t ws_size, hipStream_t stream) {
  const float* x = (const float*)d_in[0];      // [4,2048,1024]
  const float* wqkv = (const float*)d_in[1];   // [1024,3072]
  const float* bqkv = (const float*)d_in[2];   // [3072]
  const float* wproj = (const float*)d_in[3];  // [1024,1024]
  const float* bproj = (const float*)d_in[4];  // [1024]
  float* out = (float*)d_out;                  // [4,2048,1024]
  char* ws = (char*)d_ws;

  bf16_t* xb = (bf16_t*)(ws);                 // 16 MiB [8192][1024]
  bf16_t* wqkvT = (bf16_t*)(ws + 16777216);   // 6 MiB  [3072][1024]
  bf16_t* wprojT = (bf16_t*)(ws + 23068672);  // 2 MiB  [1024][1024]
  bf16_t* Qb = (bf16_t*)(ws + 25165824);      // 16 MiB [B,H,S,Dh]
  bf16_t* Kb = (bf16_t*)(ws + 41943040);      // 16 MiB [B,H,S,Dh]
  bf16_t* Vtb = (bf16_t*)(ws + 58720256);     // 16 MiB [B,H,Dh,S]
  bf16_t* attnb = (bf16_t*)(ws + 75497472);   // 16 MiB [8192][1024]

  cast_f32_to_bf16<<<8192, 256, 0, stream>>>(x, xb, (8192 * 1024) / 4);
  transpose_cast<<<dim3(96, 32), 256, 0, stream>>>(wqkv, wqkvT, 1024, 3072);
  transpose_cast<<<dim3(32, 32), 256, 0, stream>>>(wproj, wprojT, 1024, 1024);
  gemm_bf16_128<0><<<dim3(64, 24), 256, 0, stream>>>(xb, wqkvT, bqkv, Qb, Kb, Vtb, nullptr,
                                                     8192, 3072, 1024);
  attn_flash4<<<dim3(64, 16), 256, 0, stream>>>(Qb, Kb, Vtb, attnb);
  gemm_bf16_128<1><<<dim3(64, 8), 256, 0, stream>>>(attnb, wprojT, bproj, nullptr, nullptr,
                                                    nullptr, out, 8192, 1024, 1024);
}